// Round 7
// baseline (286.578 us; speedup 1.0000x reference)
//
#include <hip/hip_runtime.h>

#define NN 50000
#define NE 800000
#define DD 128
#define NB 196    // node buckets of 256 nodes: ceil(NN/256)
#define NBLK 98   // edge chunks: ceil(NE/CHUNK)
#define CHUNK 8192
#define FCAP 5120 // finalize LDS staging cap (mean 4096 + 16 sigma)

// NOTE (harness contract): integer inputs are delivered as int32 —
// edge_index is `const int*` with 2*NE elements.

// ---------------- h = x @ W.T  (fp32 vector GEMM, W transposed in LDS) ------
__global__ __launch_bounds__(512) void k_gemm(const float* __restrict__ x,
                                              const float* __restrict__ W,
                                              float* __restrict__ h) {
  __shared__ float Wt[DD * DD];  // Wt[k*128 + j] = W[j*128 + k]
  const int t = threadIdx.x;
  {
    const int j = t >> 2;
    const int kb = (t & 3) * 32;
    const float4* wrow = (const float4*)(W + j * DD + kb);
#pragma unroll
    for (int i = 0; i < 8; ++i) {
      float4 v = wrow[i];
      int k = kb + i * 4;
      Wt[(k + 0) * DD + j] = v.x;
      Wt[(k + 1) * DD + j] = v.y;
      Wt[(k + 2) * DD + j] = v.z;
      Wt[(k + 3) * DD + j] = v.w;
    }
  }
  __syncthreads();

  const int cg = t & 31;
  const int rg = t >> 5;  // 0..15
  const int c0 = cg * 4;
  const int rbase = blockIdx.x * 64 + rg * 4;

  float acc[4][4];
#pragma unroll
  for (int a = 0; a < 4; ++a)
#pragma unroll
    for (int c = 0; c < 4; ++c) acc[a][c] = 0.f;

  const float* xp[4];
#pragma unroll
  for (int rr = 0; rr < 4; ++rr) {
    int r = rbase + rr;
    if (r > NN - 1) r = NN - 1;  // clamp loads; stores guarded below
    xp[rr] = x + (size_t)r * DD;
  }

  for (int k = 0; k < DD; k += 4) {
    float4 xv[4];
#pragma unroll
    for (int rr = 0; rr < 4; ++rr) xv[rr] = *(const float4*)(xp[rr] + k);
#pragma unroll
    for (int kk = 0; kk < 4; ++kk) {
      float4 w = *(const float4*)(&Wt[(k + kk) * DD + c0]);
#pragma unroll
      for (int rr = 0; rr < 4; ++rr) {
        float a = (&xv[rr].x)[kk];
        acc[rr][0] += a * w.x;
        acc[rr][1] += a * w.y;
        acc[rr][2] += a * w.z;
        acc[rr][3] += a * w.w;
      }
    }
  }
#pragma unroll
  for (int rr = 0; rr < 4; ++rr) {
    int r = rbase + rr;
    if (r < NN) {
      *(float4*)(h + (size_t)r * DD + c0) =
          make_float4(acc[rr][0], acc[rr][1], acc[rr][2], acc[rr][3]);
    }
  }
}

// ---------------- A1: per-(bucket,block) counts (LDS hist, no global atomics)
__global__ __launch_bounds__(256) void k_count(const int* __restrict__ ei,
                                               int* __restrict__ cnt_mat) {
  __shared__ int hist[NB];
  const int t = threadIdx.x;
  const int blk = blockIdx.x;
  if (t < NB) hist[t] = 0;
  __syncthreads();
  const int e0 = blk * CHUNK;
  for (int i = t; i < CHUNK; i += 256) {
    int e = e0 + i;
    if (e < NE) {
      int d = ei[NE + e];
      atomicAdd(&hist[d >> 8], 1);
    }
  }
  __syncthreads();
  if (t < NB) cnt_mat[t * NBLK + blk] = hist[t];  // bucket-major
}

// ---------------- A2: exclusive scan of cnt_mat (19208 ints), in place ------
__global__ __launch_bounds__(256) void k_scanmat(int* __restrict__ cnt_mat,
                                                 int* __restrict__ row_start) {
  __shared__ int s[256];
  __shared__ int carry;
  const int t = threadIdx.x;
  if (t == 0) carry = 0;
  __syncthreads();
  const int total = NB * NBLK;
  for (int base = 0; base < total; base += 256) {
    int i = base + t;
    int v = (i < total) ? cnt_mat[i] : 0;
    s[t] = v;
    __syncthreads();
    for (int off = 1; off < 256; off <<= 1) {
      int u = (t >= off) ? s[t - off] : 0;
      __syncthreads();
      s[t] += u;
      __syncthreads();
    }
    if (i < total) cnt_mat[i] = carry + s[t] - v;  // exclusive prefix
    __syncthreads();
    if (t == 255) carry += s[255];
    __syncthreads();
  }
  if (t == 0) row_start[NN] = NE;
}

// ---------------- A3: place packed (dst&255)<<16|src into dense segments ----
// Each (bucket,block) sub-segment is written by exactly one block, dense ->
// full 64B lines, no cross-XCD partial-line amplification (vs 53MB WRITE_SIZE
// of the old random scatter).
__global__ __launch_bounds__(256) void k_place(const int* __restrict__ ei,
                                               const int* __restrict__ cnt_mat,
                                               unsigned int* __restrict__ pairs) {
  __shared__ int cur[NB];
  const int t = threadIdx.x;
  const int blk = blockIdx.x;
  if (t < NB) cur[t] = cnt_mat[t * NBLK + blk];
  __syncthreads();
  const int e0 = blk * CHUNK;
  for (int i = t; i < CHUNK; i += 256) {
    int e = e0 + i;
    if (e < NE) {
      int sN = ei[e];
      int d = ei[NE + e];
      int p = atomicAdd(&cur[d >> 8], 1);
      pairs[p] = (unsigned int)sN | ((unsigned int)(d & 255) << 16);
    }
  }
}

// ---------------- B: per-bucket finalize: row_start + csr (ushort) ----------
// One block per bucket (~4096 pairs): LDS stage, local 256-node hist + scan,
// dense csr writes confined to this bucket's segment.
__global__ __launch_bounds__(256) void k_finalize(const unsigned int* __restrict__ pairs,
                                                  const int* __restrict__ cnt_mat,
                                                  int* __restrict__ row_start,
                                                  unsigned short* __restrict__ csr) {
  __shared__ int cnt[256];
  __shared__ int s2[256];
  __shared__ unsigned int stage[FCAP];
  const int b = blockIdx.x;
  const int t = threadIdx.x;
  const int beg = cnt_mat[b * NBLK];
  const int end = (b == NB - 1) ? NE : cnt_mat[(b + 1) * NBLK];
  const int count = end - beg;
  cnt[t] = 0;
  __syncthreads();
  const unsigned int* bp = pairs + beg;
  const bool fit = (count <= FCAP);  // true with overwhelming probability
  for (int i = t; i < count; i += 256) {
    unsigned int w = bp[i];
    if (fit) stage[i] = w;
    atomicAdd(&cnt[(w >> 16) & 255], 1);
  }
  __syncthreads();
  int v = cnt[t];
  s2[t] = v;
  __syncthreads();
  for (int off = 1; off < 256; off <<= 1) {
    int u = (t >= off) ? s2[t - off] : 0;
    __syncthreads();
    s2[t] += u;
    __syncthreads();
  }
  const int excl = s2[t] - v;
  const int node = b * 256 + t;
  if (node < NN) row_start[node] = beg + excl;
  cnt[t] = excl;  // becomes the local cursor
  __syncthreads();
  for (int i = t; i < count; i += 256) {
    unsigned int w = fit ? stage[i] : bp[i];
    int p = atomicAdd(&cnt[(w >> 16) & 255], 1);
    csr[beg + p] = (unsigned short)(w & 0xffffu);
  }
}

// ---------------- per-node gather-reduce (v2, kept: left top-5 last round) --
__global__ __launch_bounds__(256) void k_gather(const float* __restrict__ h,
                                                const unsigned short* __restrict__ csr,
                                                const int* __restrict__ row_start,
                                                const float* __restrict__ bias,
                                                float* __restrict__ out) {
  const int node = blockIdx.x * 4 + (threadIdx.x >> 6);
  const int lane = threadIdx.x & 63;
  const int half = lane >> 5;   // edge parity handled by this half-wave
  const int sub = lane & 31;    // dims [sub*4, sub*4+4)
  const float* __restrict__ hs = h + sub * 4;

  const int beg = row_start[node];
  const int end = row_start[node + 1];

  float4 acc = make_float4(0.f, 0.f, 0.f, 0.f);
  int j = beg;
  for (; j + 8 <= end; j += 8) {
    int s0 = csr[j + 0 + half];
    int s1 = csr[j + 2 + half];
    int s2 = csr[j + 4 + half];
    int s3 = csr[j + 6 + half];
    const float4 v0 = *(const float4*)(hs + (size_t)s0 * DD);
    const float4 v1 = *(const float4*)(hs + (size_t)s1 * DD);
    const float4 v2 = *(const float4*)(hs + (size_t)s2 * DD);
    const float4 v3 = *(const float4*)(hs + (size_t)s3 * DD);
    acc.x += (v0.x + v1.x) + (v2.x + v3.x);
    acc.y += (v0.y + v1.y) + (v2.y + v3.y);
    acc.z += (v0.z + v1.z) + (v2.z + v3.z);
    acc.w += (v0.w + v1.w) + (v2.w + v3.w);
  }
  for (int i = j + half; i < end; i += 2) {
    int s = csr[i];
    const float4 v = *(const float4*)(hs + (size_t)s * DD);
    acc.x += v.x;
    acc.y += v.y;
    acc.z += v.z;
    acc.w += v.w;
  }
  acc.x += __shfl_xor(acc.x, 32, 64);
  acc.y += __shfl_xor(acc.y, 32, 64);
  acc.z += __shfl_xor(acc.z, 32, 64);
  acc.w += __shfl_xor(acc.w, 32, 64);

  if (half == 0) {
    const float4 bb = *(const float4*)(bias + sub * 4);
    acc.x += bb.x;
    acc.y += bb.y;
    acc.z += bb.z;
    acc.w += bb.w;
    *(float4*)(out + (size_t)node * DD + sub * 4) = acc;
  }
}

// ---------------- launch ------------------------------------------------------
extern "C" void kernel_launch(void* const* d_in, const int* in_sizes, int n_in,
                              void* d_out, int out_size, void* d_ws, size_t ws_size,
                              hipStream_t stream) {
  const float* x = (const float*)d_in[0];
  const int* ei = (const int*)d_in[1];  // [2, NE], int32 per harness contract
  const float* W = (const float*)d_in[2];
  const float* b = (const float*)d_in[3];
  float* out = (float*)d_out;

  // workspace carve-up (~30.7 MB): h | pairs | cnt_mat | row_start | csr
  float* h = (float*)d_ws;                              // NN*DD f32 (25.6MB)
  unsigned int* pairs = (unsigned int*)(h + (size_t)NN * DD);  // NE u32 (3.2MB)
  int* cnt_mat = (int*)(pairs + NE);                    // NB*NBLK (76.8KB)
  int* row_start = cnt_mat + NB * NBLK;                 // NN+1
  unsigned short* csr = (unsigned short*)(row_start + NN + 1);  // NE u16 (1.6MB)

  k_gemm<<<(NN + 63) / 64, 512, 0, stream>>>(x, W, h);
  k_count<<<NBLK, 256, 0, stream>>>(ei, cnt_mat);
  k_scanmat<<<1, 256, 0, stream>>>(cnt_mat, row_start);
  k_place<<<NBLK, 256, 0, stream>>>(ei, cnt_mat, pairs);
  k_finalize<<<NB, 256, 0, stream>>>(pairs, cnt_mat, row_start, csr);
  k_gather<<<NN / 4, 256, 0, stream>>>(h, csr, row_start, b, out);
}

// Round 9
// 209.043 us; speedup vs baseline: 1.3709x; 1.3709x over previous
//
#include <hip/hip_runtime.h>

#define NN 50000
#define NE 800000
#define DD 128
#define NB 196    // node buckets of 256 nodes: ceil(NN/256)
#define NBLK 98   // edge chunks: ceil(NE/CHUNK)
#define CHUNK 8192
#define FCAP 5120 // finalize LDS staging cap (mean 4096 + 16 sigma)
#define SCAN_TOTAL (NB * NBLK)                  // 19208
#define SCAN_CHUNKS ((SCAN_TOTAL + 255) / 256)  // 76

// NOTE (harness contract): integer inputs are delivered as int32 —
// edge_index is `const int*` with 2*NE elements.

// ---------------- h = x @ W.T  (fp32 vector GEMM, W transposed in LDS) ------
__global__ __launch_bounds__(512) void k_gemm(const float* __restrict__ x,
                                              const float* __restrict__ W,
                                              float* __restrict__ h) {
  __shared__ float Wt[DD * DD];  // Wt[k*128 + j] = W[j*128 + k]
  const int t = threadIdx.x;
  {
    const int j = t >> 2;
    const int kb = (t & 3) * 32;
    const float4* wrow = (const float4*)(W + j * DD + kb);
#pragma unroll
    for (int i = 0; i < 8; ++i) {
      float4 v = wrow[i];
      int k = kb + i * 4;
      Wt[(k + 0) * DD + j] = v.x;
      Wt[(k + 1) * DD + j] = v.y;
      Wt[(k + 2) * DD + j] = v.z;
      Wt[(k + 3) * DD + j] = v.w;
    }
  }
  __syncthreads();

  const int cg = t & 31;
  const int rg = t >> 5;  // 0..15
  const int c0 = cg * 4;
  const int rbase = blockIdx.x * 64 + rg * 4;

  float acc[4][4];
#pragma unroll
  for (int a = 0; a < 4; ++a)
#pragma unroll
    for (int c = 0; c < 4; ++c) acc[a][c] = 0.f;

  const float* xp[4];
#pragma unroll
  for (int rr = 0; rr < 4; ++rr) {
    int r = rbase + rr;
    if (r > NN - 1) r = NN - 1;  // clamp loads; stores guarded below
    xp[rr] = x + (size_t)r * DD;
  }

  for (int k = 0; k < DD; k += 4) {
    float4 xv[4];
#pragma unroll
    for (int rr = 0; rr < 4; ++rr) xv[rr] = *(const float4*)(xp[rr] + k);
#pragma unroll
    for (int kk = 0; kk < 4; ++kk) {
      float4 w = *(const float4*)(&Wt[(k + kk) * DD + c0]);
#pragma unroll
      for (int rr = 0; rr < 4; ++rr) {
        float a = (&xv[rr].x)[kk];
        acc[rr][0] += a * w.x;
        acc[rr][1] += a * w.y;
        acc[rr][2] += a * w.z;
        acc[rr][3] += a * w.w;
      }
    }
  }
#pragma unroll
  for (int rr = 0; rr < 4; ++rr) {
    int r = rbase + rr;
    if (r < NN) {
      *(float4*)(h + (size_t)r * DD + c0) =
          make_float4(acc[rr][0], acc[rr][1], acc[rr][2], acc[rr][3]);
    }
  }
}

// ---------------- A1: per-(bucket,block) counts (LDS hist, no global atomics)
__global__ __launch_bounds__(256) void k_count(const int* __restrict__ ei,
                                               int* __restrict__ cnt_mat) {
  __shared__ int hist[NB];
  const int t = threadIdx.x;
  const int blk = blockIdx.x;
  if (t < NB) hist[t] = 0;
  __syncthreads();
  const int e0 = blk * CHUNK;
  for (int i = t; i < CHUNK; i += 256) {
    int e = e0 + i;
    if (e < NE) {
      int d = ei[NE + e];
      atomicAdd(&hist[d >> 8], 1);
    }
  }
  __syncthreads();
  if (t < NB) cnt_mat[t * NBLK + blk] = hist[t];  // bucket-major
}

// ---------------- A2a: chunk-local exclusive scan (76 blocks, parallel) -----
// Round-7 post-mortem: single-block k_scanmat was 84us (VALUBusy 0.01%,
// serial barrier/L2-latency chain on 1 CU). Hierarchical scan; the "add
// chunk offsets" pass is folded into the consumers (cnt_mat[i] + bsum[i>>8]).
__global__ __launch_bounds__(256) void k_scan_a(int* __restrict__ cnt_mat,
                                                int* __restrict__ bsum) {
  __shared__ int s[256];
  const int t = threadIdx.x;
  const int i = blockIdx.x * 256 + t;
  int v = (i < SCAN_TOTAL) ? cnt_mat[i] : 0;
  s[t] = v;
  __syncthreads();
  for (int off = 1; off < 256; off <<= 1) {
    int u = (t >= off) ? s[t - off] : 0;
    __syncthreads();
    s[t] += u;
    __syncthreads();
  }
  if (i < SCAN_TOTAL) cnt_mat[i] = s[t] - v;  // chunk-local exclusive
  if (t == 255) bsum[blockIdx.x] = s[255];    // chunk total
}

// ---------------- A2b: scan the 76 chunk totals (1 tiny block) --------------
__global__ __launch_bounds__(256) void k_scan_b(int* __restrict__ bsum,
                                                int* __restrict__ row_start) {
  __shared__ int s[256];
  const int t = threadIdx.x;
  int v = (t < SCAN_CHUNKS) ? bsum[t] : 0;
  s[t] = v;
  __syncthreads();
  for (int off = 1; off < 256; off <<= 1) {
    int u = (t >= off) ? s[t - off] : 0;
    __syncthreads();
    s[t] += u;
    __syncthreads();
  }
  if (t < SCAN_CHUNKS) bsum[t] = s[t] - v;  // exclusive chunk offsets
  if (t == 0) row_start[NN] = NE;
}

// ---------------- A3: place packed (dst&255)<<16|src into dense segments ----
// Each (bucket,block) sub-segment is written by exactly one block, dense ->
// full 64B lines (old random scatter: 53MB WRITE_SIZE, 16x amplification).
__global__ __launch_bounds__(256) void k_place(const int* __restrict__ ei,
                                               const int* __restrict__ cnt_mat,
                                               const int* __restrict__ bsum,
                                               unsigned int* __restrict__ pairs) {
  __shared__ int cur[NB];
  const int t = threadIdx.x;
  const int blk = blockIdx.x;
  if (t < NB) {
    int idx = t * NBLK + blk;
    cur[t] = cnt_mat[idx] + bsum[idx >> 8];  // global exclusive prefix
  }
  __syncthreads();
  const int e0 = blk * CHUNK;
  for (int i = t; i < CHUNK; i += 256) {
    int e = e0 + i;
    if (e < NE) {
      int sN = ei[e];
      int d = ei[NE + e];
      int p = atomicAdd(&cur[d >> 8], 1);
      pairs[p] = (unsigned int)sN | ((unsigned int)(d & 255) << 16);
    }
  }
}

// ---------------- B: per-bucket finalize: row_start + csr (ushort) ----------
__global__ __launch_bounds__(256) void k_finalize(const unsigned int* __restrict__ pairs,
                                                  const int* __restrict__ cnt_mat,
                                                  const int* __restrict__ bsum,
                                                  int* __restrict__ row_start,
                                                  unsigned short* __restrict__ csr) {
  __shared__ int cnt[256];
  __shared__ int s2[256];
  __shared__ unsigned int stage[FCAP];
  const int b = blockIdx.x;
  const int t = threadIdx.x;
  const int i0 = b * NBLK;
  const int beg = cnt_mat[i0] + bsum[i0 >> 8];
  const int end = (b == NB - 1) ? NE : (cnt_mat[i0 + NBLK] + bsum[(i0 + NBLK) >> 8]);
  const int count = end - beg;
  cnt[t] = 0;
  __syncthreads();
  const unsigned int* bp = pairs + beg;
  const bool fit = (count <= FCAP);  // true with overwhelming probability
  for (int i = t; i < count; i += 256) {
    unsigned int w = bp[i];
    if (fit) stage[i] = w;
    atomicAdd(&cnt[(w >> 16) & 255], 1);
  }
  __syncthreads();
  int v = cnt[t];
  s2[t] = v;
  __syncthreads();
  for (int off = 1; off < 256; off <<= 1) {
    int u = (t >= off) ? s2[t - off] : 0;
    __syncthreads();
    s2[t] += u;
    __syncthreads();
  }
  const int excl = s2[t] - v;
  const int node = b * 256 + t;
  if (node < NN) row_start[node] = beg + excl;
  cnt[t] = excl;  // becomes the local cursor
  __syncthreads();
  for (int i = t; i < count; i += 256) {
    unsigned int w = fit ? stage[i] : bp[i];
    int p = atomicAdd(&cnt[(w >> 16) & 255], 1);
    csr[beg + p] = (unsigned short)(w & 0xffffu);
  }
}

// ---------------- per-node gather-reduce (v2) --------------------------------
__global__ __launch_bounds__(256) void k_gather(const float* __restrict__ h,
                                                const unsigned short* __restrict__ csr,
                                                const int* __restrict__ row_start,
                                                const float* __restrict__ bias,
                                                float* __restrict__ out) {
  const int node = blockIdx.x * 4 + (threadIdx.x >> 6);
  const int lane = threadIdx.x & 63;
  const int half = lane >> 5;   // edge parity handled by this half-wave
  const int sub = lane & 31;    // dims [sub*4, sub*4+4)
  const float* __restrict__ hs = h + sub * 4;

  const int beg = row_start[node];
  const int end = row_start[node + 1];

  float4 acc = make_float4(0.f, 0.f, 0.f, 0.f);
  int j = beg;
  for (; j + 8 <= end; j += 8) {
    int s0 = csr[j + 0 + half];
    int s1 = csr[j + 2 + half];
    int s2 = csr[j + 4 + half];
    int s3 = csr[j + 6 + half];
    const float4 v0 = *(const float4*)(hs + (size_t)s0 * DD);
    const float4 v1 = *(const float4*)(hs + (size_t)s1 * DD);
    const float4 v2 = *(const float4*)(hs + (size_t)s2 * DD);
    const float4 v3 = *(const float4*)(hs + (size_t)s3 * DD);
    acc.x += (v0.x + v1.x) + (v2.x + v3.x);
    acc.y += (v0.y + v1.y) + (v2.y + v3.y);
    acc.z += (v0.z + v1.z) + (v2.z + v3.z);
    acc.w += (v0.w + v1.w) + (v2.w + v3.w);
  }
  for (int i = j + half; i < end; i += 2) {
    int s = csr[i];
    const float4 v = *(const float4*)(hs + (size_t)s * DD);
    acc.x += v.x;
    acc.y += v.y;
    acc.z += v.z;
    acc.w += v.w;
  }
  acc.x += __shfl_xor(acc.x, 32, 64);
  acc.y += __shfl_xor(acc.y, 32, 64);
  acc.z += __shfl_xor(acc.z, 32, 64);
  acc.w += __shfl_xor(acc.w, 32, 64);

  if (half == 0) {
    const float4 bb = *(const float4*)(bias + sub * 4);
    acc.x += bb.x;
    acc.y += bb.y;
    acc.z += bb.z;
    acc.w += bb.w;
    *(float4*)(out + (size_t)node * DD + sub * 4) = acc;
  }
}

// ---------------- launch ------------------------------------------------------
extern "C" void kernel_launch(void* const* d_in, const int* in_sizes, int n_in,
                              void* d_out, int out_size, void* d_ws, size_t ws_size,
                              hipStream_t stream) {
  const float* x = (const float*)d_in[0];
  const int* ei = (const int*)d_in[1];  // [2, NE], int32 per harness contract
  const float* W = (const float*)d_in[2];
  const float* b = (const float*)d_in[3];
  float* out = (float*)d_out;

  // workspace carve-up (~30.7 MB): h | pairs | cnt_mat | bsum | row_start | csr
  float* h = (float*)d_ws;                              // NN*DD f32 (25.6MB)
  unsigned int* pairs = (unsigned int*)(h + (size_t)NN * DD);  // NE u32 (3.2MB)
  int* cnt_mat = (int*)(pairs + NE);                    // NB*NBLK (76.8KB)
  int* bsum = cnt_mat + SCAN_TOTAL;                     // 76 (+pad)
  int* row_start = bsum + 256;                          // NN+1
  unsigned short* csr = (unsigned short*)(row_start + NN + 1);  // NE u16 (1.6MB)

  k_gemm<<<(NN + 63) / 64, 512, 0, stream>>>(x, W, h);
  k_count<<<NBLK, 256, 0, stream>>>(ei, cnt_mat);
  k_scan_a<<<SCAN_CHUNKS, 256, 0, stream>>>(cnt_mat, bsum);
  k_scan_b<<<1, 256, 0, stream>>>(bsum, row_start);
  k_place<<<NBLK, 256, 0, stream>>>(ei, cnt_mat, bsum, pairs);
  k_finalize<<<NB, 256, 0, stream>>>(pairs, cnt_mat, bsum, row_start, csr);
  k_gather<<<NN / 4, 256, 0, stream>>>(h, csr, row_start, b, out);
}

// Round 16
// 198.321 us; speedup vs baseline: 1.4450x; 1.0541x over previous
//
#include <hip/hip_runtime.h>
#include <hip/hip_fp16.h>

#define NN 50000
#define NE 800000
#define DD 128
#define NB 196    // node buckets of 256 nodes: ceil(NN/256)
#define NBLK 98   // edge chunks: ceil(NE/CHUNK)
#define CHUNK 8192
#define FCAP 5120 // finalize LDS staging cap (mean 4096 + 16 sigma)
#define SCAN_TOTAL (NB * NBLK)                  // 19208
#define SCAN_CHUNKS ((SCAN_TOTAL + 255) / 256)  // 76

// NOTE (harness contract): integer inputs are delivered as int32 —
// edge_index is `const int*` with 2*NE elements.

// ---------------- h16 = fp16(x @ W.T)  (fp32 math, fp16 store) --------------
// Round-9: gather is traffic-bound (FETCH 173MB, 47% HBM). Halving the row
// to 256B (fp16) halves random-read traffic; accumulation stays fp32.
__global__ __launch_bounds__(512) void k_gemm(const float* __restrict__ x,
                                              const float* __restrict__ W,
                                              __half* __restrict__ h16) {
  __shared__ float Wt[DD * DD];  // Wt[k*128 + j] = W[j*128 + k]
  const int t = threadIdx.x;
  {
    const int j = t >> 2;
    const int kb = (t & 3) * 32;
    const float4* wrow = (const float4*)(W + j * DD + kb);
#pragma unroll
    for (int i = 0; i < 8; ++i) {
      float4 v = wrow[i];
      int k = kb + i * 4;
      Wt[(k + 0) * DD + j] = v.x;
      Wt[(k + 1) * DD + j] = v.y;
      Wt[(k + 2) * DD + j] = v.z;
      Wt[(k + 3) * DD + j] = v.w;
    }
  }
  __syncthreads();

  const int cg = t & 31;
  const int rg = t >> 5;  // 0..15
  const int c0 = cg * 4;
  const int rbase = blockIdx.x * 64 + rg * 4;

  float acc[4][4];
#pragma unroll
  for (int a = 0; a < 4; ++a)
#pragma unroll
    for (int c = 0; c < 4; ++c) acc[a][c] = 0.f;

  const float* xp[4];
#pragma unroll
  for (int rr = 0; rr < 4; ++rr) {
    int r = rbase + rr;
    if (r > NN - 1) r = NN - 1;  // clamp loads; stores guarded below
    xp[rr] = x + (size_t)r * DD;
  }

  for (int k = 0; k < DD; k += 4) {
    float4 xv[4];
#pragma unroll
    for (int rr = 0; rr < 4; ++rr) xv[rr] = *(const float4*)(xp[rr] + k);
#pragma unroll
    for (int kk = 0; kk < 4; ++kk) {
      float4 w = *(const float4*)(&Wt[(k + kk) * DD + c0]);
#pragma unroll
      for (int rr = 0; rr < 4; ++rr) {
        float a = (&xv[rr].x)[kk];
        acc[rr][0] += a * w.x;
        acc[rr][1] += a * w.y;
        acc[rr][2] += a * w.z;
        acc[rr][3] += a * w.w;
      }
    }
  }
#pragma unroll
  for (int rr = 0; rr < 4; ++rr) {
    int r = rbase + rr;
    if (r < NN) {
      __half2 p0 = __floats2half2_rn(acc[rr][0], acc[rr][1]);
      __half2 p1 = __floats2half2_rn(acc[rr][2], acc[rr][3]);
      union { __half2 h2[2]; uint2 u; } pk;
      pk.h2[0] = p0;
      pk.h2[1] = p1;
      *(uint2*)(h16 + (size_t)r * DD + c0) = pk.u;  // 8B aligned store
    }
  }
}

// ---------------- A1: per-(bucket,block) counts (LDS hist, no global atomics)
__global__ __launch_bounds__(256) void k_count(const int* __restrict__ ei,
                                               int* __restrict__ cnt_mat) {
  __shared__ int hist[NB];
  const int t = threadIdx.x;
  const int blk = blockIdx.x;
  if (t < NB) hist[t] = 0;
  __syncthreads();
  const int e0 = blk * CHUNK;
  for (int i = t; i < CHUNK; i += 256) {
    int e = e0 + i;
    if (e < NE) {
      int d = ei[NE + e];
      atomicAdd(&hist[d >> 8], 1);
    }
  }
  __syncthreads();
  if (t < NB) cnt_mat[t * NBLK + blk] = hist[t];  // bucket-major
}

// ---------------- A2a: chunk-local exclusive scan (76 blocks, parallel) -----
__global__ __launch_bounds__(256) void k_scan_a(int* __restrict__ cnt_mat,
                                                int* __restrict__ bsum) {
  __shared__ int s[256];
  const int t = threadIdx.x;
  const int i = blockIdx.x * 256 + t;
  int v = (i < SCAN_TOTAL) ? cnt_mat[i] : 0;
  s[t] = v;
  __syncthreads();
  for (int off = 1; off < 256; off <<= 1) {
    int u = (t >= off) ? s[t - off] : 0;
    __syncthreads();
    s[t] += u;
    __syncthreads();
  }
  if (i < SCAN_TOTAL) cnt_mat[i] = s[t] - v;  // chunk-local exclusive
  if (t == 255) bsum[blockIdx.x] = s[255];    // chunk total
}

// ---------------- A2b: scan the 76 chunk totals (1 tiny block) --------------
__global__ __launch_bounds__(256) void k_scan_b(int* __restrict__ bsum,
                                                int* __restrict__ row_start) {
  __shared__ int s[256];
  const int t = threadIdx.x;
  int v = (t < SCAN_CHUNKS) ? bsum[t] : 0;
  s[t] = v;
  __syncthreads();
  for (int off = 1; off < 256; off <<= 1) {
    int u = (t >= off) ? s[t - off] : 0;
    __syncthreads();
    s[t] += u;
    __syncthreads();
  }
  if (t < SCAN_CHUNKS) bsum[t] = s[t] - v;  // exclusive chunk offsets
  if (t == 0) row_start[NN] = NE;
}

// ---------------- A3: place packed (dst&255)<<16|src into dense segments ----
__global__ __launch_bounds__(256) void k_place(const int* __restrict__ ei,
                                               const int* __restrict__ cnt_mat,
                                               const int* __restrict__ bsum,
                                               unsigned int* __restrict__ pairs) {
  __shared__ int cur[NB];
  const int t = threadIdx.x;
  const int blk = blockIdx.x;
  if (t < NB) {
    int idx = t * NBLK + blk;
    cur[t] = cnt_mat[idx] + bsum[idx >> 8];  // global exclusive prefix
  }
  __syncthreads();
  const int e0 = blk * CHUNK;
  for (int i = t; i < CHUNK; i += 256) {
    int e = e0 + i;
    if (e < NE) {
      int sN = ei[e];
      int d = ei[NE + e];
      int p = atomicAdd(&cur[d >> 8], 1);
      pairs[p] = (unsigned int)sN | ((unsigned int)(d & 255) << 16);
    }
  }
}

// ---------------- B: per-bucket finalize: row_start + csr (ushort) ----------
__global__ __launch_bounds__(256) void k_finalize(const unsigned int* __restrict__ pairs,
                                                  const int* __restrict__ cnt_mat,
                                                  const int* __restrict__ bsum,
                                                  int* __restrict__ row_start,
                                                  unsigned short* __restrict__ csr) {
  __shared__ int cnt[256];
  __shared__ int s2[256];
  __shared__ unsigned int stage[FCAP];
  const int b = blockIdx.x;
  const int t = threadIdx.x;
  const int i0 = b * NBLK;
  const int beg = cnt_mat[i0] + bsum[i0 >> 8];
  const int end = (b == NB - 1) ? NE : (cnt_mat[i0 + NBLK] + bsum[(i0 + NBLK) >> 8]);
  const int count = end - beg;
  cnt[t] = 0;
  __syncthreads();
  const unsigned int* bp = pairs + beg;
  const bool fit = (count <= FCAP);  // true with overwhelming probability
  for (int i = t; i < count; i += 256) {
    unsigned int w = bp[i];
    if (fit) stage[i] = w;
    atomicAdd(&cnt[(w >> 16) & 255], 1);
  }
  __syncthreads();
  int v = cnt[t];
  s2[t] = v;
  __syncthreads();
  for (int off = 1; off < 256; off <<= 1) {
    int u = (t >= off) ? s2[t - off] : 0;
    __syncthreads();
    s2[t] += u;
    __syncthreads();
  }
  const int excl = s2[t] - v;
  const int node = b * 256 + t;
  if (node < NN) row_start[node] = beg + excl;
  cnt[t] = excl;  // becomes the local cursor
  __syncthreads();
  for (int i = t; i < count; i += 256) {
    unsigned int w = fit ? stage[i] : bp[i];
    int p = atomicAdd(&cnt[(w >> 16) & 255], 1);
    csr[beg + p] = (unsigned short)(w & 0xffffu);
  }
}

// ---------------- per-node gather-reduce, v3 (fp16 table, 8-deep MLP) -------
// par = edge-parity half-wave (renamed from `half`: hip_fp16.h typedefs
// `half` globally). lane covers dims [sub*4, sub*4+4) as uint2;
// fp32 accumulate; float4 output.
__global__ __launch_bounds__(256) void k_gather(const __half* __restrict__ h16,
                                                const unsigned short* __restrict__ csr,
                                                const int* __restrict__ row_start,
                                                const float* __restrict__ bias,
                                                float* __restrict__ out) {
  const int node = blockIdx.x * 4 + (threadIdx.x >> 6);
  const int lane = threadIdx.x & 63;
  const int par = lane >> 5;    // edge parity handled by this half-wave
  const int sub = lane & 31;    // dims [sub*4, sub*4+4)
  const __half* __restrict__ hp = h16 + sub * 4;

  const int beg = row_start[node];
  const int end = row_start[node + 1];

  float4 acc = make_float4(0.f, 0.f, 0.f, 0.f);

#define ACCUM(rw)                                                   \
  {                                                                 \
    __half2 a_ = *(__half2*)&(rw).x;                                \
    __half2 b_ = *(__half2*)&(rw).y;                                \
    float2 fa_ = __half22float2(a_);                                \
    float2 fb_ = __half22float2(b_);                                \
    acc.x += fa_.x; acc.y += fa_.y; acc.z += fb_.x; acc.w += fb_.y; \
  }

  int j = beg;
  for (; j + 16 <= end; j += 16) {
    int s0 = csr[j + 0 + par];
    int s1 = csr[j + 2 + par];
    int s2 = csr[j + 4 + par];
    int s3 = csr[j + 6 + par];
    int s4 = csr[j + 8 + par];
    int s5 = csr[j + 10 + par];
    int s6 = csr[j + 12 + par];
    int s7 = csr[j + 14 + par];
    uint2 r0 = *(const uint2*)(hp + (size_t)s0 * DD);
    uint2 r1 = *(const uint2*)(hp + (size_t)s1 * DD);
    uint2 r2 = *(const uint2*)(hp + (size_t)s2 * DD);
    uint2 r3 = *(const uint2*)(hp + (size_t)s3 * DD);
    uint2 r4 = *(const uint2*)(hp + (size_t)s4 * DD);
    uint2 r5 = *(const uint2*)(hp + (size_t)s5 * DD);
    uint2 r6 = *(const uint2*)(hp + (size_t)s6 * DD);
    uint2 r7 = *(const uint2*)(hp + (size_t)s7 * DD);
    ACCUM(r0) ACCUM(r1) ACCUM(r2) ACCUM(r3)
    ACCUM(r4) ACCUM(r5) ACCUM(r6) ACCUM(r7)
  }
  for (int i = j + par; i < end; i += 2) {
    int s = csr[i];
    uint2 r = *(const uint2*)(hp + (size_t)s * DD);
    ACCUM(r)
  }
#undef ACCUM

  acc.x += __shfl_xor(acc.x, 32, 64);
  acc.y += __shfl_xor(acc.y, 32, 64);
  acc.z += __shfl_xor(acc.z, 32, 64);
  acc.w += __shfl_xor(acc.w, 32, 64);

  if (par == 0) {
    const float4 bb = *(const float4*)(bias + sub * 4);
    acc.x += bb.x;
    acc.y += bb.y;
    acc.z += bb.z;
    acc.w += bb.w;
    *(float4*)(out + (size_t)node * DD + sub * 4) = acc;
  }
}

// ---------------- launch ------------------------------------------------------
extern "C" void kernel_launch(void* const* d_in, const int* in_sizes, int n_in,
                              void* d_out, int out_size, void* d_ws, size_t ws_size,
                              hipStream_t stream) {
  const float* x = (const float*)d_in[0];
  const int* ei = (const int*)d_in[1];  // [2, NE], int32 per harness contract
  const float* W = (const float*)d_in[2];
  const float* b = (const float*)d_in[3];
  float* out = (float*)d_out;

  // workspace carve-up (~17.9 MB): h16 | pairs | cnt_mat | bsum | row_start | csr
  __half* h16 = (__half*)d_ws;                          // NN*DD f16 (12.8MB)
  unsigned int* pairs = (unsigned int*)(h16 + (size_t)NN * DD);  // NE u32 (3.2MB)
  int* cnt_mat = (int*)(pairs + NE);                    // NB*NBLK (76.8KB)
  int* bsum = cnt_mat + SCAN_TOTAL;                     // 76 (+pad)
  int* row_start = bsum + 256;                          // NN+1
  unsigned short* csr = (unsigned short*)(row_start + NN + 1);  // NE u16 (1.6MB)

  k_gemm<<<(NN + 63) / 64, 512, 0, stream>>>(x, W, h16);
  k_count<<<NBLK, 256, 0, stream>>>(ei, cnt_mat);
  k_scan_a<<<SCAN_CHUNKS, 256, 0, stream>>>(cnt_mat, bsum);
  k_scan_b<<<1, 256, 0, stream>>>(bsum, row_start);
  k_place<<<NBLK, 256, 0, stream>>>(ei, cnt_mat, bsum, pairs);
  k_finalize<<<NB, 256, 0, stream>>>(pairs, cnt_mat, bsum, row_start, csr);
  k_gather<<<NN / 4, 256, 0, stream>>>(h16, csr, row_start, b, out);
}